// Round 3
// baseline (83.979 us; speedup 1.0000x reference)
//
#include <hip/hip_runtime.h>
#include <cmath>

#define IMG_W 1024
#define NT    128           // threads per block (2 waves); each lane owns one column
#define OC    (NT - 6)      // 122 output columns per block (lanes 3..124)
#define ROWS  12            // output rows per block
#define STEPS (ROWS + 6)    // source rows swept (pipeline warmup = 6)
#define PADW  (NT + 6)      // LDS row width incl. halo slots

// separable Gaussian: w(ky,kx) = gv[ky]*gh[kx], 1/(8*pi) folded into gv
struct GK { float gh[7]; float gv[7]; };

__global__ __launch_bounds__(NT)
void mind_sweep(const float* __restrict__ img1, const float* __restrict__ img2,
                float* __restrict__ out, GK gk)
{
    // double-buffered row of pointwise fields (H,V,D,U) as float4
    __shared__ float4 buf[2][PADW];     // 2*134*16 = 4288 B

    const int tx = (int)threadIdx.x;
    const int X0 = 7 + (int)blockIdx.x * OC;    // first output col of block
    const int Y0 = 7 + (int)blockIdx.y * ROWS;  // first output row of block

    const int sx_raw = X0 - 3 + tx;             // source col this lane loads
    const int sx  = min(sx_raw, 1023);          // clamp only affects masked lanes
    const int sxp = sx ^ 512;                   // the only in-bounds x-shift source
    const bool xok = (tx >= 3) && (tx <= NT - 4) && (sx_raw <= 1016);

    // fold the x-mask into per-lane weight pairs once (zero mask VALU in-loop):
    // tap kx touches source col sx_raw + kx - 3; "lo" (col<512) means shift +1 valid
    float glx[7], ghx[7];
    #pragma unroll
    for (int kx = 0; kx < 7; ++kx) {
        const bool lo = (((sx_raw + kx - 3) & 512) == 0);
        glx[kx] = lo ? gk.gh[kx] : 0.f;
        ghx[kx] = lo ? 0.f : gk.gh[kx];
    }

    // 7-deep sliding windows of the 6 horizontally-convolved fields
    float wHlo[7] = {0}, wHhi[7] = {0}, wV[7] = {0},
          wDlo[7] = {0}, wDhi[7] = {0}, wU[7] = {0};
    float tsum = 0.f;

    #pragma unroll
    for (int s = 0; s < STEPS; ++s) {
        // ---- pointwise fields for source row Y0-3+s (registers only) ----
        const int sr  = min(Y0 - 3 + s, 1023);  // clamp only affects masked rows
        const int srp = sr ^ 512;               // the only in-bounds y-shift source
        const float* __restrict__ r2  = img2 + sr  * IMG_W;
        const float* __restrict__ r2p = img2 + srp * IMG_W;
        const float* __restrict__ r1  = img1 + sr  * IMG_W;
        const float* __restrict__ r1p = img1 + srp * IMG_W;
        const float a  = r2[sx], b = r2[sxp], c = r2p[sx], d = r2p[sxp];
        const float u  = r1[sx], ub = r1[sxp], uc = r1p[sx];
        const float a2 = a * a;
        const float tb = a - b, tc = a - c, td = a - d;
        const float su = u - ub, sv = u - uc;
        float4 f;
        f.x = fmaf(tb, tb, -a2);                         // H: (a-b)^2 - a^2
        f.y = fmaf(tc, tc, -a2);                         // V
        f.z = fmaf(td, td, -a2);                         // D
        f.w = fmaf(u, u + u, fmaf(su, su, sv * sv));     // U: 4*Vimg integrand
        buf[s & 1][tx + 3] = f;
        __syncthreads();   // single barrier/step; 2 slots make WAR safe

        // ---- horizontal 7-tap conv (lanes 3..124 valid; edges garbage->masked) ----
        float hHlo = 0, hHhi = 0, hV = 0, hDlo = 0, hDhi = 0, hU = 0;
        #pragma unroll
        for (int kx = 0; kx < 7; ++kx) {
            const float4 g = buf[s & 1][tx + kx];
            hHlo = fmaf(glx[kx],  g.x, hHlo);
            hHhi = fmaf(ghx[kx],  g.x, hHhi);
            hV   = fmaf(gk.gh[kx], g.y, hV);
            hDlo = fmaf(glx[kx],  g.z, hDlo);
            hDhi = fmaf(ghx[kx],  g.z, hDhi);
            hU   = fmaf(gk.gh[kx], g.w, hU);
        }
        // push into windows
        #pragma unroll
        for (int i = 0; i < 6; ++i) {
            wHlo[i] = wHlo[i+1]; wHhi[i] = wHhi[i+1]; wV[i] = wV[i+1];
            wDlo[i] = wDlo[i+1]; wDhi[i] = wDhi[i+1]; wU[i] = wU[i+1];
        }
        wHlo[6] = hHlo; wHhi[6] = hHhi; wV[6] = hV;
        wDlo[6] = hDlo; wDhi[6] = hDhi; wU[6] = hU;

        // ---- vertical conv + epilogue for output row y = Y0 + s - 6 ----
        if (s >= 6) {
            const int y = Y0 + s - 6;
            if (y <= 1017) {                    // wave-uniform gate
                float Ph=0,Qh=0,Pv=0,Qv=0,Ppp=0,Ppm=0,Pmp=0,Pmm=0,V4=0;
                #pragma unroll
                for (int ky = 0; ky < 7; ++ky) {
                    const float g = gk.gv[ky];
                    const bool ylo = (((y - 3 + ky) & 512) == 0);  // uniform
                    const float wl = ylo ? g : 0.f;
                    const float wh = ylo ? 0.f : g;
                    Ph  = fmaf(g,  wHlo[ky], Ph);
                    Qh  = fmaf(g,  wHhi[ky], Qh);
                    Pv  = fmaf(wl, wV[ky],   Pv);
                    Qv  = fmaf(wh, wV[ky],   Qv);
                    Ppp = fmaf(wl, wDlo[ky], Ppp);
                    Ppm = fmaf(wh, wDlo[ky], Ppm);
                    Pmp = fmaf(wl, wDhi[ky], Pmp);
                    Pmm = fmaf(wh, wDhi[ky], Pmm);
                    V4  = fmaf(g,  wU[ky],   V4);
                }
                const float V = fmaf(V4, 0.25f, 1e-5f);
                const float invV = 1.0f / V;
                float M = fminf(0.f, Ph);
                M = fminf(M, Qh);  M = fminf(M, Pv);  M = fminf(M, Qv);
                M = fminf(M, Ppp); M = fminf(M, Pmp); M = fminf(M, Ppm); M = fminf(M, Pmm);
                const float pix = 72.f * __expf(M * invV)
                    + __expf((M - Ph ) * invV) + __expf((M - Qh ) * invV)
                    + __expf((M - Pv ) * invV) + __expf((M - Qv ) * invV)
                    + __expf((M - Ppp) * invV) + __expf((M - Pmp) * invV)
                    + __expf((M - Ppm) * invV) + __expf((M - Pmm) * invV);
                tsum += xok ? pix : 0.f;        // cndmask: masked lanes' garbage dies here
            }
        }
    }

    // ---- block reduction + one atomic ----
    #pragma unroll
    for (int off = 32; off > 0; off >>= 1)
        tsum += __shfl_down(tsum, off, 64);
    __shared__ float wsum[2];
    __syncthreads();
    if ((tx & 63) == 0) wsum[tx >> 6] = tsum;
    __syncthreads();
    if (tx == 0)
        atomicAdd(out, (wsum[0] + wsum[1]) * (1.0f / 81688800.0f));  // 80*1011*1010
}

extern "C" void kernel_launch(void* const* d_in, const int* in_sizes, int n_in,
                              void* d_out, int out_size, void* d_ws, size_t ws_size,
                              hipStream_t stream) {
    const float* img1 = (const float*)d_in[0];
    const float* img2 = (const float*)d_in[1];
    float* out = (float*)d_out;

    GK gk;
    for (int i = 0; i < 7; ++i) {
        const double d = i - 3;
        gk.gh[i] = (float)std::exp(-(d * d) / 8.0);
        gk.gv[i] = (float)(std::exp(-(d * d) / 8.0) / (8.0 * M_PI));
    }

    hipMemsetAsync(d_out, 0, sizeof(float), stream);
    dim3 block(NT, 1);
    dim3 grid(9, 85);   // 9*122=1098 >= 1010 cols ; 85*12=1020 >= 1011 rows
    mind_sweep<<<grid, block, 0, stream>>>(img1, img2, out, gk);
}